// Round 2
// baseline (7112.493 us; speedup 1.0000x reference)
//
#include <hip/hip_runtime.h>
#include <math.h>

#define BB 64
#define SS 200
#define TT 25
#define VV 32000
#define EE 256
#define HH 256
#define HID 512

// ---------------------------------------------------------------------------
// prep: pack w_hh (768x256) -> wT[k4][768][4] so scan reads float4 along K
// ---------------------------------------------------------------------------
__global__ void k_whh_pack(const float* __restrict__ wf, const float* __restrict__ wb,
                           float* __restrict__ oTf, float* __restrict__ oTb) {
    int gid = blockIdx.x * 256 + threadIdx.x;
    if (gid >= 2 * 768 * 256) return;
    const float* w = (gid < 768 * 256) ? wf : wb;
    float* o = (gid < 768 * 256) ? oTf : oTb;
    int g = gid % (768 * 256);
    int j = g >> 8;        // 0..767 output row of w_hh
    int kk = g & 255;      // 0..255
    o[(kk >> 2) * 3072 + j * 4 + (kk & 3)] = w[g];
}

// ---------------------------------------------------------------------------
// gi GEMM: C[12800][768] = gather(emb by src_flat) @ W^T + bias
// ---------------------------------------------------------------------------
__global__ __launch_bounds__(256) void k_gemm_gi(const int* __restrict__ src,
                                                 const float* __restrict__ emb,
                                                 const float* __restrict__ W,
                                                 const float* __restrict__ bias,
                                                 float* __restrict__ C) {
    __shared__ float As[32][68];
    __shared__ float Ws[32][68];
    __shared__ int toks[64];
    int tid = threadIdx.x, bx = blockIdx.x, by = blockIdx.y;
    if (tid < 64) toks[tid] = src[by * 64 + tid];
    __syncthreads();
    int tx = tid & 15, ty = tid >> 4;
    float acc[4][4] = {};
    for (int k0 = 0; k0 < 256; k0 += 32) {
#pragma unroll
        for (int l = 0; l < 2; ++l) {
            int f = tid + l * 256;
            int r = f >> 3, c4 = f & 7;
            float4 v = *(const float4*)(emb + (size_t)toks[r] * EE + k0 + c4 * 4);
            As[c4 * 4 + 0][r] = v.x; As[c4 * 4 + 1][r] = v.y;
            As[c4 * 4 + 2][r] = v.z; As[c4 * 4 + 3][r] = v.w;
            float4 w = *(const float4*)(W + (size_t)(bx * 64 + r) * 256 + k0 + c4 * 4);
            Ws[c4 * 4 + 0][r] = w.x; Ws[c4 * 4 + 1][r] = w.y;
            Ws[c4 * 4 + 2][r] = w.z; Ws[c4 * 4 + 3][r] = w.w;
        }
        __syncthreads();
#pragma unroll
        for (int kk = 0; kk < 32; ++kk) {
            float4 a = *(const float4*)&As[kk][ty * 4];
            float4 w = *(const float4*)&Ws[kk][tx * 4];
            acc[0][0] += a.x * w.x; acc[0][1] += a.x * w.y; acc[0][2] += a.x * w.z; acc[0][3] += a.x * w.w;
            acc[1][0] += a.y * w.x; acc[1][1] += a.y * w.y; acc[1][2] += a.y * w.z; acc[1][3] += a.y * w.w;
            acc[2][0] += a.z * w.x; acc[2][1] += a.z * w.y; acc[2][2] += a.z * w.z; acc[2][3] += a.z * w.w;
            acc[3][0] += a.w * w.x; acc[3][1] += a.w * w.y; acc[3][2] += a.w * w.z; acc[3][3] += a.w * w.w;
        }
        __syncthreads();
    }
#pragma unroll
    for (int i = 0; i < 4; ++i)
#pragma unroll
        for (int j = 0; j < 4; ++j) {
            int m = by * 64 + ty * 4 + i, n = bx * 64 + tx * 4 + j;
            C[(size_t)m * 768 + n] = acc[i][j] + bias[n];
        }
}

// ---------------------------------------------------------------------------
// recurrent scan, K-split: 64 blocks x 1024 threads (16 waves/CU, 4/SIMD).
// thread (e = tid&255, kq = tid>>8) computes partial dots of rows
// {e, 256+e, 512+e} over K in [64*kq, 64*kq+64) for both chains.
// Partials combined through LDS; waves 0-3 (kq==0) do gate math.
// ---------------------------------------------------------------------------
__global__ __launch_bounds__(1024) void k_scan(const float* __restrict__ giF,
                                               const float* __restrict__ giB,
                                               const float* __restrict__ wTf,
                                               const float* __restrict__ wTb,
                                               const float* __restrict__ bhhf,
                                               const float* __restrict__ bhhb,
                                               float* __restrict__ states) {
    __shared__ float hs[2][256];
    __shared__ float accs[4][2][768];  // [kq][chain][row]  24.5 KB
    int bid = blockIdx.x, tid = threadIdx.x;
    int dir = bid >> 5, pair = bid & 31;
    int j0 = pair * 2, j1 = pair * 2 + 1;
    const float* gi = dir ? giB : giF;
    const float* wT = dir ? wTb : wTf;
    const float* bhh = dir ? bhhb : bhhf;
    int e = tid & 255;
    int kq = tid >> 8;
    float br = 0.f, bz = 0.f, bn = 0.f;
    if (kq == 0) { br = bhh[e]; bz = bhh[256 + e]; bn = bhh[512 + e]; }
    if (kq < 2) hs[kq][e] = 0.f;
    __syncthreads();
    for (int s = 0; s < SS; ++s) {
        int srow = dir ? (SS - 1 - s) : s;
        // hoist gi loads (only combine threads need them; latency hides under FMAs)
        float gir0 = 0, giz0 = 0, gin0 = 0, gir1 = 0, giz1 = 0, gin1 = 0;
        if (kq == 0) {
            const float* g0 = gi + ((size_t)srow * 64 + j0) * 768;
            const float* g1 = gi + ((size_t)srow * 64 + j1) * 768;
            gir0 = g0[e]; giz0 = g0[256 + e]; gin0 = g0[512 + e];
            gir1 = g1[e]; giz1 = g1[256 + e]; gin1 = g1[512 + e];
        }
        float ar0 = 0, az0 = 0, an0 = 0, ar1 = 0, az1 = 0, an1 = 0;
        int k4b = kq * 16;
#pragma unroll
        for (int k4 = 0; k4 < 16; ++k4) {
            int kk = k4b + k4;
            const float* wp = wT + (size_t)kk * 3072;
            float4 wr = *(const float4*)(wp + e * 4);
            float4 wz = *(const float4*)(wp + (256 + e) * 4);
            float4 wn = *(const float4*)(wp + (512 + e) * 4);
            float4 h0 = *(const float4*)&hs[0][kk * 4];
            float4 h1 = *(const float4*)&hs[1][kk * 4];
            ar0 += h0.x * wr.x + h0.y * wr.y + h0.z * wr.z + h0.w * wr.w;
            az0 += h0.x * wz.x + h0.y * wz.y + h0.z * wz.z + h0.w * wz.w;
            an0 += h0.x * wn.x + h0.y * wn.y + h0.z * wn.z + h0.w * wn.w;
            ar1 += h1.x * wr.x + h1.y * wr.y + h1.z * wr.z + h1.w * wr.w;
            az1 += h1.x * wz.x + h1.y * wz.y + h1.z * wz.z + h1.w * wz.w;
            an1 += h1.x * wn.x + h1.y * wn.y + h1.z * wn.z + h1.w * wn.w;
        }
        accs[kq][0][e] = ar0; accs[kq][0][256 + e] = az0; accs[kq][0][512 + e] = an0;
        accs[kq][1][e] = ar1; accs[kq][1][256 + e] = az1; accs[kq][1][512 + e] = an1;
        __syncthreads();
        if (kq == 0) {
            float sr0 = accs[0][0][e] + accs[1][0][e] + accs[2][0][e] + accs[3][0][e];
            float sz0 = accs[0][0][256 + e] + accs[1][0][256 + e] + accs[2][0][256 + e] + accs[3][0][256 + e];
            float sn0 = accs[0][0][512 + e] + accs[1][0][512 + e] + accs[2][0][512 + e] + accs[3][0][512 + e];
            float sr1 = accs[0][1][e] + accs[1][1][e] + accs[2][1][e] + accs[3][1][e];
            float sz1 = accs[0][1][256 + e] + accs[1][1][256 + e] + accs[2][1][256 + e] + accs[3][1][256 + e];
            float sn1 = accs[0][1][512 + e] + accs[1][1][512 + e] + accs[2][1][512 + e] + accs[3][1][512 + e];
            float hold0 = hs[0][e], hold1 = hs[1][e];
            float r0 = 1.f / (1.f + expf(-(gir0 + sr0 + br)));
            float z0 = 1.f / (1.f + expf(-(giz0 + sz0 + bz)));
            float n0 = tanhf(gin0 + r0 * (sn0 + bn));
            float hn0 = (1.f - z0) * n0 + z0 * hold0;
            float r1 = 1.f / (1.f + expf(-(gir1 + sr1 + br)));
            float z1 = 1.f / (1.f + expf(-(giz1 + sz1 + bz)));
            float n1 = tanhf(gin1 + r1 * (sn1 + bn));
            float hn1 = (1.f - z1) * n1 + z1 * hold1;
            int off = dir ? 256 : 0;
            states[((size_t)srow * 64 + j0) * HID + off + e] = hn0;
            states[((size_t)srow * 64 + j1) * HID + off + e] = hn1;
            hs[0][e] = hn0; hs[1][e] = hn1;
        }
        __syncthreads();
    }
}

// ---------------------------------------------------------------------------
// ench (scrambled enc_hidden reshape) + G = ench @ W2^T + b2
// ---------------------------------------------------------------------------
__global__ __launch_bounds__(256) void k_ench(const float* __restrict__ states,
                                              const float* __restrict__ W2,
                                              const float* __restrict__ b2,
                                              float* __restrict__ ench,
                                              float* __restrict__ G) {
    __shared__ float es[512];
    int b = blockIdx.x, t = threadIdx.x;
    int p0 = 2 * b, p1 = 2 * b + 1;
    float v0 = (p0 < 64) ? states[((size_t)(SS - 1) * 64 + p0) * HID + t]
                         : states[((size_t)(p0 - 64)) * HID + 256 + t];
    float v1 = (p1 < 64) ? states[((size_t)(SS - 1) * 64 + p1) * HID + t]
                         : states[((size_t)(p1 - 64)) * HID + 256 + t];
    es[t] = v0; es[256 + t] = v1;
    ench[b * 512 + t] = v0; ench[b * 512 + 256 + t] = v1;
    __syncthreads();
    float a0 = 0, a1 = 0;
    for (int k = 0; k < 512; k += 4) {
        float4 e = *(const float4*)&es[k];
        float4 w0 = *(const float4*)(W2 + (size_t)t * 512 + k);
        float4 w1 = *(const float4*)(W2 + (size_t)(256 + t) * 512 + k);
        a0 += e.x * w0.x + e.y * w0.y + e.z * w0.z + e.w * w0.w;
        a1 += e.x * w1.x + e.y * w1.y + e.z * w1.z + e.w * w1.w;
    }
    G[b * 512 + t] = a0 + b2[t];
    G[b * 512 + 256 + t] = a1 + b2[256 + t];
}

// ---------------------------------------------------------------------------
// gate GEMM: states2 = states * sigmoid(states @ W1^T + b1 + G[b])
// ---------------------------------------------------------------------------
__global__ __launch_bounds__(256) void k_gate(const float* __restrict__ A,
                                              const float* __restrict__ W1,
                                              const float* __restrict__ b1,
                                              const float* __restrict__ G,
                                              float* __restrict__ out) {
    __shared__ float As[32][68];
    __shared__ float Ws[32][68];
    int tid = threadIdx.x, bx = blockIdx.x, by = blockIdx.y;
    int tx = tid & 15, ty = tid >> 4;
    float acc[4][4] = {};
    for (int k0 = 0; k0 < 512; k0 += 32) {
#pragma unroll
        for (int l = 0; l < 2; ++l) {
            int f = tid + l * 256;
            int r = f >> 3, c4 = f & 7;
            float4 v = *(const float4*)(A + ((size_t)by * 64 + r) * 512 + k0 + c4 * 4);
            As[c4 * 4 + 0][r] = v.x; As[c4 * 4 + 1][r] = v.y;
            As[c4 * 4 + 2][r] = v.z; As[c4 * 4 + 3][r] = v.w;
            float4 w = *(const float4*)(W1 + (size_t)(bx * 64 + r) * 512 + k0 + c4 * 4);
            Ws[c4 * 4 + 0][r] = w.x; Ws[c4 * 4 + 1][r] = w.y;
            Ws[c4 * 4 + 2][r] = w.z; Ws[c4 * 4 + 3][r] = w.w;
        }
        __syncthreads();
#pragma unroll
        for (int kk = 0; kk < 32; ++kk) {
            float4 a = *(const float4*)&As[kk][ty * 4];
            float4 w = *(const float4*)&Ws[kk][tx * 4];
            acc[0][0] += a.x * w.x; acc[0][1] += a.x * w.y; acc[0][2] += a.x * w.z; acc[0][3] += a.x * w.w;
            acc[1][0] += a.y * w.x; acc[1][1] += a.y * w.y; acc[1][2] += a.y * w.z; acc[1][3] += a.y * w.w;
            acc[2][0] += a.z * w.x; acc[2][1] += a.z * w.y; acc[2][2] += a.z * w.z; acc[2][3] += a.z * w.w;
            acc[3][0] += a.w * w.x; acc[3][1] += a.w * w.y; acc[3][2] += a.w * w.z; acc[3][3] += a.w * w.w;
        }
        __syncthreads();
    }
#pragma unroll
    for (int i = 0; i < 4; ++i)
#pragma unroll
        for (int j = 0; j < 4; ++j) {
            int m = by * 64 + ty * 4 + i, n = bx * 64 + tx * 4 + j;
            int b = ty * 4 + i;  // m % 64
            float x = acc[i][j] + b1[n] + G[(size_t)b * 512 + n];
            float g = 1.f / (1.f + expf(-x));
            out[(size_t)m * 512 + n] = A[(size_t)m * 512 + n] * g;
        }
}

// ---------------------------------------------------------------------------
// attn1[m] = dot(states2[m], Wa1) + ba1   (one wave per row)
// ---------------------------------------------------------------------------
__global__ __launch_bounds__(256) void k_attn1(const float* __restrict__ s2,
                                               const float* __restrict__ Wa1,
                                               const float* __restrict__ ba1,
                                               float* __restrict__ attn1) {
    int wid = threadIdx.x >> 6, lane = threadIdx.x & 63;
    int m = blockIdx.x * 4 + wid;
    const float* row = s2 + (size_t)m * 512;
    float acc = 0;
    for (int i = lane; i < 512; i += 64) acc += row[i] * Wa1[i];
    for (int off = 32; off > 0; off >>= 1) acc += __shfl_down(acc, off, 64);
    if (lane == 0) attn1[m] = acc + ba1[0];
}

// ---------------------------------------------------------------------------
// decoder init: h = ench, loss = 0
// ---------------------------------------------------------------------------
__global__ void k_dec_init(const float* __restrict__ ench, float* __restrict__ h,
                           float* __restrict__ loss) {
    int gid = blockIdx.x * 256 + threadIdx.x;
    if (gid < 64 * 512) h[gid] = ench[gid];
    if (gid == 0) loss[0] = 0.f;
}

// ---------------------------------------------------------------------------
// attention scores + faithful scrambled softmax.  block = one softmax row r.
// ---------------------------------------------------------------------------
__global__ __launch_bounds__(256) void k_attn_soft(const float* __restrict__ h,
                                                   const float* __restrict__ Wa2,
                                                   const float* __restrict__ ba2,
                                                   const float* __restrict__ attn1,
                                                   float* __restrict__ aw) {
    __shared__ float a2s[64];
    __shared__ float red[256];
    int r = blockIdx.x, t = threadIdx.x;
    int b = t >> 2, q = t & 3;
    float part = 0;
    for (int i = 0; i < 128; ++i) {
        int k = q + 4 * i;
        part += h[(size_t)b * 512 + k] * Wa2[k];
    }
    red[t] = part;
    __syncthreads();
    if (t < 64) a2s[t] = red[t * 4] + red[t * 4 + 1] + red[t * 4 + 2] + red[t * 4 + 3] + ba2[0];
    __syncthreads();
    int iflat = r * 200 + t;
    float val = (t < 200) ? attn1[iflat] + a2s[iflat & 63] : -3.4e38f;
    red[t] = val;
    __syncthreads();
    for (int s = 128; s > 0; s >>= 1) {
        if (t < s) red[t] = fmaxf(red[t], red[t + s]);
        __syncthreads();
    }
    float mx = red[0];
    __syncthreads();
    float e = (t < 200) ? expf(val - mx) : 0.f;
    red[t] = e;
    __syncthreads();
    for (int s = 128; s > 0; s >>= 1) {
        if (t < s) red[t] += red[t + s];
        __syncthreads();
    }
    float sum = red[0];
    if (t < 200) aw[iflat] = e / sum;
}

// ---------------------------------------------------------------------------
// context + xcat build, split over HID halves: grid (64, 2)
// ---------------------------------------------------------------------------
__global__ __launch_bounds__(256) void k_ctx(const float* __restrict__ aw,
                                             const float* __restrict__ s2,
                                             const float* __restrict__ emb,
                                             const int* __restrict__ trg,
                                             int step, float* __restrict__ xcat) {
    __shared__ float awl[200];
    int b = blockIdx.x, half = blockIdx.y, t = threadIdx.x;
    if (t < 200) awl[t] = aw[t * 64 + b];
    if (half == 0) {
        int wi = trg[b * TT + step];
        xcat[b * 768 + t] = emb[(size_t)wi * EE + t];
    }
    __syncthreads();
    const float* base = s2 + (size_t)b * 512 + half * 256 + t;
    float a = 0;
#pragma unroll 8
    for (int s = 0; s < SS; ++s) a += awl[s] * base[(size_t)s * 64 * 512];
    xcat[b * 768 + 256 + half * 256 + t] = a;
}

// ---------------------------------------------------------------------------
// decoder GRU GEMMs (unchanged)
// ---------------------------------------------------------------------------
__global__ __launch_bounds__(256) void k_grud(const float* __restrict__ xcat,
                                              const float* __restrict__ h,
                                              const float* __restrict__ wih,
                                              const float* __restrict__ whh,
                                              const float* __restrict__ bih,
                                              const float* __restrict__ bhh,
                                              float* __restrict__ gid_,
                                              float* __restrict__ ghd) {
    __shared__ float As[32][68];
    __shared__ float Ws[32][36];
    int z = blockIdx.x;
    bool second = z >= 48;
    const float* A = second ? h : xcat;
    const float* W = second ? whh : wih;
    const float* bias = second ? bhh : bih;
    float* out = second ? ghd : gid_;
    int K = second ? 512 : 768;
    int n0 = (second ? z - 48 : z) * 32;
    int tid = threadIdx.x;
    int tx = tid & 15, ty = tid >> 4;
    float acc[4][2] = {};
    for (int k0 = 0; k0 < K; k0 += 32) {
#pragma unroll
        for (int l = 0; l < 2; ++l) {
            int f = tid + l * 256;
            int r = f >> 3, c4 = f & 7;
            float4 v = *(const float4*)(A + (size_t)r * K + k0 + c4 * 4);
            As[c4 * 4 + 0][r] = v.x; As[c4 * 4 + 1][r] = v.y;
            As[c4 * 4 + 2][r] = v.z; As[c4 * 4 + 3][r] = v.w;
        }
        {
            int r = tid >> 3, c4 = tid & 7;
            float4 w = *(const float4*)(W + (size_t)(n0 + r) * K + k0 + c4 * 4);
            Ws[c4 * 4 + 0][r] = w.x; Ws[c4 * 4 + 1][r] = w.y;
            Ws[c4 * 4 + 2][r] = w.z; Ws[c4 * 4 + 3][r] = w.w;
        }
        __syncthreads();
#pragma unroll
        for (int kk = 0; kk < 32; ++kk) {
            float4 a = *(const float4*)&As[kk][ty * 4];
            float2 w = *(const float2*)&Ws[kk][tx * 2];
            acc[0][0] += a.x * w.x; acc[0][1] += a.x * w.y;
            acc[1][0] += a.y * w.x; acc[1][1] += a.y * w.y;
            acc[2][0] += a.z * w.x; acc[2][1] += a.z * w.y;
            acc[3][0] += a.w * w.x; acc[3][1] += a.w * w.y;
        }
        __syncthreads();
    }
#pragma unroll
    for (int i = 0; i < 4; ++i)
#pragma unroll
        for (int j = 0; j < 2; ++j) {
            int m = ty * 4 + i, n = n0 + tx * 2 + j;
            out[(size_t)m * 1536 + n] = acc[i][j] + bias[n];
        }
}

// ---------------------------------------------------------------------------
// decoder GRU elementwise update (in place on h)
// ---------------------------------------------------------------------------
__global__ void k_hnew(const float* __restrict__ gi, const float* __restrict__ gh,
                       float* __restrict__ h) {
    int gid = blockIdx.x * 256 + threadIdx.x;  // 32768
    int b = gid >> 9, k = gid & 511;
    float gir = gi[b * 1536 + k], giz = gi[b * 1536 + 512 + k], gin = gi[b * 1536 + 1024 + k];
    float ghr = gh[b * 1536 + k], ghz = gh[b * 1536 + 512 + k], ghn = gh[b * 1536 + 1024 + k];
    float r = 1.f / (1.f + expf(-(gir + ghr)));
    float z = 1.f / (1.f + expf(-(giz + ghz)));
    float n = tanhf(gin + r * ghn);
    h[gid] = (1.f - z) * n + z * h[gid];
}

// ---------------------------------------------------------------------------
// vocab GEMM fused with log-softmax partials: per block-row online (max, sumexp)
// + target-logit capture.  No logits array materialized.
// ---------------------------------------------------------------------------
__global__ __launch_bounds__(256) void k_vocab_ls(const float* __restrict__ A,
                                                  const float* __restrict__ Wv,
                                                  const float* __restrict__ bv,
                                                  const int* __restrict__ trg, int step,
                                                  float* __restrict__ pmax,
                                                  float* __restrict__ psum,
                                                  float* __restrict__ tlog) {
    __shared__ float As[32][68];
    __shared__ float Ws[32][68];
    __shared__ int tgts[64];
    int tid = threadIdx.x, bx = blockIdx.x;
    if (tid < 64) tgts[tid] = trg[tid * TT + step + 1];
    int tx = tid & 15, ty = tid >> 4;
    float acc[4][4] = {};
    for (int k0 = 0; k0 < 512; k0 += 32) {
#pragma unroll
        for (int l = 0; l < 2; ++l) {
            int f = tid + l * 256;
            int r = f >> 3, c4 = f & 7;
            float4 v = *(const float4*)(A + (size_t)r * 512 + k0 + c4 * 4);
            As[c4 * 4 + 0][r] = v.x; As[c4 * 4 + 1][r] = v.y;
            As[c4 * 4 + 2][r] = v.z; As[c4 * 4 + 3][r] = v.w;
            float4 w = *(const float4*)(Wv + (size_t)(bx * 64 + r) * 512 + k0 + c4 * 4);
            Ws[c4 * 4 + 0][r] = w.x; Ws[c4 * 4 + 1][r] = w.y;
            Ws[c4 * 4 + 2][r] = w.z; Ws[c4 * 4 + 3][r] = w.w;
        }
        __syncthreads();
#pragma unroll
        for (int kk = 0; kk < 32; ++kk) {
            float4 a = *(const float4*)&As[kk][ty * 4];
            float4 w = *(const float4*)&Ws[kk][tx * 4];
            acc[0][0] += a.x * w.x; acc[0][1] += a.x * w.y; acc[0][2] += a.x * w.z; acc[0][3] += a.x * w.w;
            acc[1][0] += a.y * w.x; acc[1][1] += a.y * w.y; acc[1][2] += a.y * w.z; acc[1][3] += a.y * w.w;
            acc[2][0] += a.z * w.x; acc[2][1] += a.z * w.y; acc[2][2] += a.z * w.z; acc[2][3] += a.z * w.w;
            acc[3][0] += a.w * w.x; acc[3][1] += a.w * w.y; acc[3][2] += a.w * w.z; acc[3][3] += a.w * w.w;
        }
        __syncthreads();
    }
    // epilogue: add bias, per-row local (max, sumexp), target capture
    float bvv[4];
#pragma unroll
    for (int j = 0; j < 4; ++j) bvv[j] = bv[bx * 64 + tx * 4 + j];
#pragma unroll
    for (int i = 0; i < 4; ++i) {
        int row = ty * 4 + i;
        int tgt = tgts[row];
        float l0 = acc[i][0] + bvv[0], l1 = acc[i][1] + bvv[1];
        float l2 = acc[i][2] + bvv[2], l3 = acc[i][3] + bvv[3];
        int n0 = bx * 64 + tx * 4;
        if (tgt == n0) tlog[row] = l0;
        else if (tgt == n0 + 1) tlog[row] = l1;
        else if (tgt == n0 + 2) tlog[row] = l2;
        else if (tgt == n0 + 3) tlog[row] = l3;
        float m = fmaxf(fmaxf(l0, l1), fmaxf(l2, l3));
        float sE = expf(l0 - m) + expf(l1 - m) + expf(l2 - m) + expf(l3 - m);
        // combine across the 16 tx-lanes (contiguous 16-lane groups)
#pragma unroll
        for (int off = 1; off < 16; off <<= 1) {
            float mo = __shfl_xor(m, off, 64);
            float so = __shfl_xor(sE, off, 64);
            float mn = fmaxf(m, mo);
            sE = sE * expf(m - mn) + so * expf(mo - mn);
            m = mn;
        }
        if (tx == 0) {
            pmax[bx * 64 + row] = m;
            psum[bx * 64 + row] = sE;
        }
    }
}

// ---------------------------------------------------------------------------
// loss reduce: one block combines 500 partials per row + target logit
// ---------------------------------------------------------------------------
__global__ __launch_bounds__(256) void k_loss(const float* __restrict__ pmax,
                                              const float* __restrict__ psum,
                                              const float* __restrict__ tlog,
                                              float* __restrict__ lossp) {
    __shared__ float red[64];
    int t = threadIdx.x;
    int b = t >> 2, q = t & 3;
    float m = -3.4e38f, sE = 0.f;
    for (int bx = q; bx < 500; bx += 4) {
        float mb = pmax[bx * 64 + b], sb = psum[bx * 64 + b];
        if (mb > m) { sE = sE * expf(m - mb) + sb; m = mb; }
        else sE += sb * expf(mb - m);
    }
#pragma unroll
    for (int off = 1; off < 4; off <<= 1) {
        float mo = __shfl_xor(m, off, 64);
        float so = __shfl_xor(sE, off, 64);
        float mn = fmaxf(m, mo);
        sE = sE * expf(m - mn) + so * expf(mo - mn);
        m = mn;
    }
    if (q == 0) red[b] = m + logf(sE) - tlog[b];
    __syncthreads();
    if (t == 0) {
        float s = 0;
        for (int i = 0; i < 64; ++i) s += red[i];
        lossp[0] += s;
    }
}

__global__ void k_final(const float* __restrict__ loss, float* __restrict__ out) {
    out[0] = loss[0] * (1.f / (64.f * 25.f));
}

// ---------------------------------------------------------------------------
extern "C" void kernel_launch(void* const* d_in, const int* in_sizes, int n_in,
                              void* d_out, int out_size, void* d_ws, size_t ws_size,
                              hipStream_t stream) {
    const int* src = (const int*)d_in[0];
    const int* trg = (const int*)d_in[1];
    const float* emb = (const float*)d_in[2];
    const float* w_ih_f = (const float*)d_in[3];
    const float* w_hh_f = (const float*)d_in[4];
    const float* b_ih_f = (const float*)d_in[5];
    const float* b_hh_f = (const float*)d_in[6];
    const float* w_ih_b = (const float*)d_in[7];
    const float* w_hh_b = (const float*)d_in[8];
    const float* b_ih_b = (const float*)d_in[9];
    const float* b_hh_b = (const float*)d_in[10];
    const float* W1 = (const float*)d_in[11];
    const float* b1 = (const float*)d_in[12];
    const float* W2 = (const float*)d_in[13];
    const float* b2 = (const float*)d_in[14];
    const float* w_ih_d = (const float*)d_in[15];
    const float* w_hh_d = (const float*)d_in[16];
    const float* b_ih_d = (const float*)d_in[17];
    const float* b_hh_d = (const float*)d_in[18];
    const float* Wv = (const float*)d_in[19];
    const float* bv = (const float*)d_in[20];
    const float* Wa1 = (const float*)d_in[21];
    const float* ba1 = (const float*)d_in[22];
    const float* Wa2 = (const float*)d_in[23];
    const float* ba2 = (const float*)d_in[24];

    float* ws = (float*)d_ws;
    float* giF = ws;                          // 12800*768
    float* giB = giF + 12800 * 768;           // 12800*768
    float* states = giB + 12800 * 768;        // 12800*512
    float* states2 = states + 12800 * 512;    // 12800*512
    float* wTf = states2 + 12800 * 512;       // 196608
    float* wTb = wTf + 196608;                // 196608
    float* ench = wTb + 196608;               // 32768
    float* G = ench + 32768;                  // 32768
    float* attn1 = G + 32768;                 // 12800
    float* aw = attn1 + 12800;                // 12800
    float* xcat = aw + 12800;                 // 49152
    float* hdec = xcat + 49152;               // 32768
    float* gid_ = hdec + 32768;               // 98304
    float* ghd = gid_ + 98304;                // 98304
    float* pmax = ghd + 98304;                // 32000
    float* psum = pmax + 32000;               // 32000
    float* tlog = psum + 32000;               // 64
    float* lossp = tlog + 64;                 // 1

    k_whh_pack<<<(2 * 768 * 256 + 255) / 256, 256, 0, stream>>>(w_hh_f, w_hh_b, wTf, wTb);
    k_gemm_gi<<<dim3(12, 200), 256, 0, stream>>>(src, emb, w_ih_f, b_ih_f, giF);
    k_gemm_gi<<<dim3(12, 200), 256, 0, stream>>>(src, emb, w_ih_b, b_ih_b, giB);
    k_scan<<<64, 1024, 0, stream>>>(giF, giB, wTf, wTb, b_hh_f, b_hh_b, states);
    k_ench<<<64, 256, 0, stream>>>(states, W2, b2, ench, G);
    k_gate<<<dim3(8, 200), 256, 0, stream>>>(states, W1, b1, G, states2);
    k_attn1<<<3200, 256, 0, stream>>>(states2, Wa1, ba1, attn1);
    k_dec_init<<<128, 256, 0, stream>>>(ench, hdec, lossp);

    for (int t = 0; t < TT - 1; ++t) {
        k_attn_soft<<<64, 256, 0, stream>>>(hdec, Wa2, ba2, attn1, aw);
        k_ctx<<<dim3(64, 2), 256, 0, stream>>>(aw, states2, emb, trg, t, xcat);
        k_grud<<<96, 256, 0, stream>>>(xcat, hdec, w_ih_d, w_hh_d, b_ih_d, b_hh_d, gid_, ghd);
        k_hnew<<<128, 256, 0, stream>>>(gid_, ghd, hdec);
        k_vocab_ls<<<500, 256, 0, stream>>>(hdec, Wv, bv, trg, t, pmax, psum, tlog);
        k_loss<<<1, 256, 0, stream>>>(pmax, psum, tlog, lossp);
    }
    k_final<<<1, 1, 0, stream>>>(lossp, (float*)d_out);
}

// Round 3
// 5681.104 us; speedup vs baseline: 1.2520x; 1.2520x over previous
//
#include <hip/hip_runtime.h>
#include <math.h>

#define BB 64
#define SS 200
#define TT 25
#define VV 32000
#define EE 256
#define HH 256
#define HID 512

typedef unsigned int u32;
typedef unsigned short u16;
typedef _Float16 half2v __attribute__((ext_vector_type(2)));
typedef short short8v __attribute__((ext_vector_type(8)));
typedef float float4v __attribute__((ext_vector_type(4)));

__device__ inline half2v u2h2(u32 u) { half2v h; __builtin_memcpy(&h, &u, 4); return h; }
__device__ inline u32 packh2(float a, float b) {
    _Float16 ha = (_Float16)a, hb = (_Float16)b;
    u16 ua, ub;
    __builtin_memcpy(&ua, &ha, 2);
    __builtin_memcpy(&ub, &hb, 2);
    return (u32)ua | ((u32)ub << 16);
}
__device__ inline u16 f2bf(float x) {
    u32 u = __float_as_uint(x);
    return (u16)((u + 0x7fff + ((u >> 16) & 1)) >> 16);
}

#if defined(__has_builtin)
#if __has_builtin(__builtin_amdgcn_fdot2)
#define HAS_FDOT2 1
#endif
#endif
#ifdef HAS_FDOT2
#define DOT2(acc, wu, hu) acc = __builtin_amdgcn_fdot2(u2h2(wu), u2h2(hu), acc, false)
#else
#define DOT2(acc, wu, hu)                                           \
    {                                                               \
        half2v _w = u2h2(wu), _h = u2h2(hu);                        \
        acc += (float)_w.x * (float)_h.x + (float)_w.y * (float)_h.y; \
    }
#endif

// ---------------------------------------------------------------------------
// generic f32 -> bf16 convert
// ---------------------------------------------------------------------------
__global__ void k_tobf(const float* __restrict__ src, u16* __restrict__ dst, int n) {
    int i = blockIdx.x * 256 + threadIdx.x;
    if (i < n) dst[i] = f2bf(src[i]);
}

// ---------------------------------------------------------------------------
// pack w_hh (768x256 f32) -> f16 pairs: out[g8][768][4] uints,
// uint q of group g8, row j = half2(w[j][8g8+2q], w[j][8g8+2q+1])
// ---------------------------------------------------------------------------
__global__ void k_whh_pack16(const float* __restrict__ wf, const float* __restrict__ wb,
                             u32* __restrict__ oF, u32* __restrict__ oB) {
    int gid = blockIdx.x * 256 + threadIdx.x;
    if (gid >= 2 * 768 * 128) return;
    const float* w = (gid < 768 * 128) ? wf : wb;
    u32* o = (gid < 768 * 128) ? oF : oB;
    int g = gid % (768 * 128);
    int j = g >> 7;      // row 0..767
    int k2 = g & 127;    // K-pair index
    float a = w[j * 256 + 2 * k2], b = w[j * 256 + 2 * k2 + 1];
    o[((size_t)(k2 >> 2) * 768 + j) * 4 + (k2 & 3)] = packh2(a, b);
}

// ---------------------------------------------------------------------------
// gi GEMM: C[12800][768] = gather(emb by src_flat) @ W^T + bias  (fp32)
// ---------------------------------------------------------------------------
__global__ __launch_bounds__(256) void k_gemm_gi(const int* __restrict__ src,
                                                 const float* __restrict__ emb,
                                                 const float* __restrict__ W,
                                                 const float* __restrict__ bias,
                                                 float* __restrict__ C) {
    __shared__ float As[32][68];
    __shared__ float Ws[32][68];
    __shared__ int toks[64];
    int tid = threadIdx.x, bx = blockIdx.x, by = blockIdx.y;
    if (tid < 64) toks[tid] = src[by * 64 + tid];
    __syncthreads();
    int tx = tid & 15, ty = tid >> 4;
    float acc[4][4] = {};
    for (int k0 = 0; k0 < 256; k0 += 32) {
#pragma unroll
        for (int l = 0; l < 2; ++l) {
            int f = tid + l * 256;
            int r = f >> 3, c4 = f & 7;
            float4 v = *(const float4*)(emb + (size_t)toks[r] * EE + k0 + c4 * 4);
            As[c4 * 4 + 0][r] = v.x; As[c4 * 4 + 1][r] = v.y;
            As[c4 * 4 + 2][r] = v.z; As[c4 * 4 + 3][r] = v.w;
            float4 w = *(const float4*)(W + (size_t)(bx * 64 + r) * 256 + k0 + c4 * 4);
            Ws[c4 * 4 + 0][r] = w.x; Ws[c4 * 4 + 1][r] = w.y;
            Ws[c4 * 4 + 2][r] = w.z; Ws[c4 * 4 + 3][r] = w.w;
        }
        __syncthreads();
#pragma unroll
        for (int kk = 0; kk < 32; ++kk) {
            float4 a = *(const float4*)&As[kk][ty * 4];
            float4 w = *(const float4*)&Ws[kk][tx * 4];
            acc[0][0] += a.x * w.x; acc[0][1] += a.x * w.y; acc[0][2] += a.x * w.z; acc[0][3] += a.x * w.w;
            acc[1][0] += a.y * w.x; acc[1][1] += a.y * w.y; acc[1][2] += a.y * w.z; acc[1][3] += a.y * w.w;
            acc[2][0] += a.z * w.x; acc[2][1] += a.z * w.y; acc[2][2] += a.z * w.z; acc[2][3] += a.z * w.w;
            acc[3][0] += a.w * w.x; acc[3][1] += a.w * w.y; acc[3][2] += a.w * w.z; acc[3][3] += a.w * w.w;
        }
        __syncthreads();
    }
#pragma unroll
    for (int i = 0; i < 4; ++i)
#pragma unroll
        for (int j = 0; j < 4; ++j) {
            int m = by * 64 + ty * 4 + i, n = bx * 64 + tx * 4 + j;
            C[(size_t)m * 768 + n] = acc[i][j] + bias[n];
        }
}

// ---------------------------------------------------------------------------
// recurrent scan: 64 blocks x 512 threads; 2 chains/block; K-split-2 via
// kq = tid>>8; W_hh in f16 (v_dot2), h in LDS (packed half2 + fp32 copy).
// ---------------------------------------------------------------------------
__global__ __launch_bounds__(512) void k_scan16(const float* __restrict__ giF,
                                                const float* __restrict__ giB,
                                                const u32* __restrict__ wTf,
                                                const u32* __restrict__ wTb,
                                                const float* __restrict__ bhhf,
                                                const float* __restrict__ bhhb,
                                                float* __restrict__ states) {
    __shared__ u32 hs2[2][128];        // packed half2 of h, per chain
    __shared__ float hsf[2][256];      // fp32 h copy
    __shared__ float pacc[2][3][256];  // kq==1 partials [chain][gate][row]
    int tid = threadIdx.x, bid = blockIdx.x;
    int e = tid & 255, kq = tid >> 8;
    int dir = bid >> 5, pair = bid & 31;
    int j0 = pair * 2, j1 = pair * 2 + 1;
    const float* gi = dir ? giB : giF;
    const u32* wT = dir ? wTb : wTf;
    const float* bhh = dir ? bhhb : bhhf;
    float br = 0.f, bz = 0.f, bn = 0.f;
    if (kq == 0) {
        br = bhh[e]; bz = bhh[256 + e]; bn = bhh[512 + e];
        hsf[0][e] = 0.f; hsf[1][e] = 0.f;
        if (e < 128) { hs2[0][e] = 0u; hs2[1][e] = 0u; }
    }
    __syncthreads();
    for (int s = 0; s < SS; ++s) {
        int srow = dir ? (SS - 1 - s) : s;
        float gir0 = 0, giz0 = 0, gin0 = 0, gir1 = 0, giz1 = 0, gin1 = 0;
        if (kq == 0) {
            const float* g0 = gi + ((size_t)srow * 64 + j0) * 768;
            const float* g1 = gi + ((size_t)srow * 64 + j1) * 768;
            gir0 = g0[e]; giz0 = g0[256 + e]; gin0 = g0[512 + e];
            gir1 = g1[e]; giz1 = g1[256 + e]; gin1 = g1[512 + e];
        }
        float ar0 = 0, az0 = 0, an0 = 0, ar1 = 0, az1 = 0, an1 = 0;
#pragma unroll 4
        for (int i = 0; i < 16; ++i) {
            int g8 = kq * 16 + i;
            const u32* wp = wT + ((size_t)g8 * 768) * 4;
            uint4 wr = *(const uint4*)(wp + (size_t)e * 4);
            uint4 wz = *(const uint4*)(wp + (size_t)(256 + e) * 4);
            uint4 wn = *(const uint4*)(wp + (size_t)(512 + e) * 4);
            uint4 h0 = *(const uint4*)&hs2[0][g8 * 4];
            uint4 h1 = *(const uint4*)&hs2[1][g8 * 4];
            DOT2(ar0, wr.x, h0.x); DOT2(ar0, wr.y, h0.y); DOT2(ar0, wr.z, h0.z); DOT2(ar0, wr.w, h0.w);
            DOT2(az0, wz.x, h0.x); DOT2(az0, wz.y, h0.y); DOT2(az0, wz.z, h0.z); DOT2(az0, wz.w, h0.w);
            DOT2(an0, wn.x, h0.x); DOT2(an0, wn.y, h0.y); DOT2(an0, wn.z, h0.z); DOT2(an0, wn.w, h0.w);
            DOT2(ar1, wr.x, h1.x); DOT2(ar1, wr.y, h1.y); DOT2(ar1, wr.z, h1.z); DOT2(ar1, wr.w, h1.w);
            DOT2(az1, wz.x, h1.x); DOT2(az1, wz.y, h1.y); DOT2(az1, wz.z, h1.z); DOT2(az1, wz.w, h1.w);
            DOT2(an1, wn.x, h1.x); DOT2(an1, wn.y, h1.y); DOT2(an1, wn.z, h1.z); DOT2(an1, wn.w, h1.w);
        }
        if (kq == 1) {
            pacc[0][0][e] = ar0; pacc[0][1][e] = az0; pacc[0][2][e] = an0;
            pacc[1][0][e] = ar1; pacc[1][1][e] = az1; pacc[1][2][e] = an1;
        }
        __syncthreads();
        if (kq == 0) {
            float sr0 = ar0 + pacc[0][0][e], sz0 = az0 + pacc[0][1][e], sn0 = an0 + pacc[0][2][e];
            float sr1 = ar1 + pacc[1][0][e], sz1 = az1 + pacc[1][1][e], sn1 = an1 + pacc[1][2][e];
            float hold0 = hsf[0][e], hold1 = hsf[1][e];
            float r0 = 1.f / (1.f + expf(-(gir0 + sr0 + br)));
            float z0 = 1.f / (1.f + expf(-(giz0 + sz0 + bz)));
            float n0 = tanhf(gin0 + r0 * (sn0 + bn));
            float hn0 = (1.f - z0) * n0 + z0 * hold0;
            float r1 = 1.f / (1.f + expf(-(gir1 + sr1 + br)));
            float z1 = 1.f / (1.f + expf(-(giz1 + sz1 + bz)));
            float n1 = tanhf(gin1 + r1 * (sn1 + bn));
            float hn1 = (1.f - z1) * n1 + z1 * hold1;
            int off = dir ? 256 : 0;
            states[((size_t)srow * 64 + j0) * HID + off + e] = hn0;
            states[((size_t)srow * 64 + j1) * HID + off + e] = hn1;
            hsf[0][e] = hn0; hsf[1][e] = hn1;
        }
        __syncthreads();
        if (tid < 128) {
            hs2[0][tid] = packh2(hsf[0][2 * tid], hsf[0][2 * tid + 1]);
            hs2[1][tid] = packh2(hsf[1][2 * tid], hsf[1][2 * tid + 1]);
        }
        __syncthreads();
    }
}

// ---------------------------------------------------------------------------
// ench (scrambled enc_hidden reshape) + G = ench @ W2^T + b2
// ---------------------------------------------------------------------------
__global__ __launch_bounds__(256) void k_ench(const float* __restrict__ states,
                                              const float* __restrict__ W2,
                                              const float* __restrict__ b2,
                                              float* __restrict__ ench,
                                              float* __restrict__ G) {
    __shared__ float es[512];
    int b = blockIdx.x, t = threadIdx.x;
    int p0 = 2 * b, p1 = 2 * b + 1;
    float v0 = (p0 < 64) ? states[((size_t)(SS - 1) * 64 + p0) * HID + t]
                         : states[((size_t)(p0 - 64)) * HID + 256 + t];
    float v1 = (p1 < 64) ? states[((size_t)(SS - 1) * 64 + p1) * HID + t]
                         : states[((size_t)(p1 - 64)) * HID + 256 + t];
    es[t] = v0; es[256 + t] = v1;
    ench[b * 512 + t] = v0; ench[b * 512 + 256 + t] = v1;
    __syncthreads();
    float a0 = 0, a1 = 0;
    for (int k = 0; k < 512; k += 4) {
        float4 e = *(const float4*)&es[k];
        float4 w0 = *(const float4*)(W2 + (size_t)t * 512 + k);
        float4 w1 = *(const float4*)(W2 + (size_t)(256 + t) * 512 + k);
        a0 += e.x * w0.x + e.y * w0.y + e.z * w0.z + e.w * w0.w;
        a1 += e.x * w1.x + e.y * w1.y + e.z * w1.z + e.w * w1.w;
    }
    G[b * 512 + t] = a0 + b2[t];
    G[b * 512 + 256 + t] = a1 + b2[256 + t];
}

// ---------------------------------------------------------------------------
// gate GEMM: states2 = states * sigmoid(states @ W1^T + b1 + G[b])  (fp32)
// ---------------------------------------------------------------------------
__global__ __launch_bounds__(256) void k_gate(const float* __restrict__ A,
                                              const float* __restrict__ W1,
                                              const float* __restrict__ b1,
                                              const float* __restrict__ G,
                                              float* __restrict__ out) {
    __shared__ float As[32][68];
    __shared__ float Ws[32][68];
    int tid = threadIdx.x, bx = blockIdx.x, by = blockIdx.y;
    int tx = tid & 15, ty = tid >> 4;
    float acc[4][4] = {};
    for (int k0 = 0; k0 < 512; k0 += 32) {
#pragma unroll
        for (int l = 0; l < 2; ++l) {
            int f = tid + l * 256;
            int r = f >> 3, c4 = f & 7;
            float4 v = *(const float4*)(A + ((size_t)by * 64 + r) * 512 + k0 + c4 * 4);
            As[c4 * 4 + 0][r] = v.x; As[c4 * 4 + 1][r] = v.y;
            As[c4 * 4 + 2][r] = v.z; As[c4 * 4 + 3][r] = v.w;
            float4 w = *(const float4*)(W1 + (size_t)(bx * 64 + r) * 512 + k0 + c4 * 4);
            Ws[c4 * 4 + 0][r] = w.x; Ws[c4 * 4 + 1][r] = w.y;
            Ws[c4 * 4 + 2][r] = w.z; Ws[c4 * 4 + 3][r] = w.w;
        }
        __syncthreads();
#pragma unroll
        for (int kk = 0; kk < 32; ++kk) {
            float4 a = *(const float4*)&As[kk][ty * 4];
            float4 w = *(const float4*)&Ws[kk][tx * 4];
            acc[0][0] += a.x * w.x; acc[0][1] += a.x * w.y; acc[0][2] += a.x * w.z; acc[0][3] += a.x * w.w;
            acc[1][0] += a.y * w.x; acc[1][1] += a.y * w.y; acc[1][2] += a.y * w.z; acc[1][3] += a.y * w.w;
            acc[2][0] += a.z * w.x; acc[2][1] += a.z * w.y; acc[2][2] += a.z * w.z; acc[2][3] += a.z * w.w;
            acc[3][0] += a.w * w.x; acc[3][1] += a.w * w.y; acc[3][2] += a.w * w.z; acc[3][3] += a.w * w.w;
        }
        __syncthreads();
    }
#pragma unroll
    for (int i = 0; i < 4; ++i)
#pragma unroll
        for (int j = 0; j < 4; ++j) {
            int m = by * 64 + ty * 4 + i, n = bx * 64 + tx * 4 + j;
            int b = ty * 4 + i;
            float x = acc[i][j] + b1[n] + G[(size_t)b * 512 + n];
            float g = 1.f / (1.f + expf(-x));
            out[(size_t)m * 512 + n] = A[(size_t)m * 512 + n] * g;
        }
}

// ---------------------------------------------------------------------------
// attn1[m] = dot(states2[m], Wa1) + ba1
// ---------------------------------------------------------------------------
__global__ __launch_bounds__(256) void k_attn1(const float* __restrict__ s2,
                                               const float* __restrict__ Wa1,
                                               const float* __restrict__ ba1,
                                               float* __restrict__ attn1) {
    int wid = threadIdx.x >> 6, lane = threadIdx.x & 63;
    int m = blockIdx.x * 4 + wid;
    const float* row = s2 + (size_t)m * 512;
    float acc = 0;
    for (int i = lane; i < 512; i += 64) acc += row[i] * Wa1[i];
    for (int off = 32; off > 0; off >>= 1) acc += __shfl_down(acc, off, 64);
    if (lane == 0) attn1[m] = acc + ba1[0];
}

// ---------------------------------------------------------------------------
// decoder init: h = ench (fp32 + bf16), loss = 0
// ---------------------------------------------------------------------------
__global__ void k_dec_init(const float* __restrict__ ench, float* __restrict__ h,
                           u16* __restrict__ hB, float* __restrict__ loss) {
    int gid = blockIdx.x * 256 + threadIdx.x;
    if (gid < 64 * 512) {
        float v = ench[gid];
        h[gid] = v;
        hB[gid] = f2bf(v);
    }
    if (gid == 0) loss[0] = 0.f;
}

// ---------------------------------------------------------------------------
// attention scores + faithful scrambled softmax
// ---------------------------------------------------------------------------
__global__ __launch_bounds__(256) void k_attn_soft(const float* __restrict__ h,
                                                   const float* __restrict__ Wa2,
                                                   const float* __restrict__ ba2,
                                                   const float* __restrict__ attn1,
                                                   float* __restrict__ aw) {
    __shared__ float a2s[64];
    __shared__ float red[256];
    int r = blockIdx.x, t = threadIdx.x;
    int b = t >> 2, q = t & 3;
    float part = 0;
    for (int i = 0; i < 128; ++i) {
        int k = q + 4 * i;
        part += h[(size_t)b * 512 + k] * Wa2[k];
    }
    red[t] = part;
    __syncthreads();
    if (t < 64) a2s[t] = red[t * 4] + red[t * 4 + 1] + red[t * 4 + 2] + red[t * 4 + 3] + ba2[0];
    __syncthreads();
    int iflat = r * 200 + t;
    float val = (t < 200) ? attn1[iflat] + a2s[iflat & 63] : -3.4e38f;
    red[t] = val;
    __syncthreads();
    for (int s = 128; s > 0; s >>= 1) {
        if (t < s) red[t] = fmaxf(red[t], red[t + s]);
        __syncthreads();
    }
    float mx = red[0];
    __syncthreads();
    float e = (t < 200) ? expf(val - mx) : 0.f;
    red[t] = e;
    __syncthreads();
    for (int s = 128; s > 0; s >>= 1) {
        if (t < s) red[t] += red[t + s];
        __syncthreads();
    }
    float sum = red[0];
    if (t < 200) aw[iflat] = e / sum;
}

// ---------------------------------------------------------------------------
// context + xcat build (bf16 out), grid (64, 2)
// ---------------------------------------------------------------------------
__global__ __launch_bounds__(256) void k_ctx(const float* __restrict__ aw,
                                             const float* __restrict__ s2,
                                             const float* __restrict__ emb,
                                             const int* __restrict__ trg,
                                             int step, u16* __restrict__ xcatB) {
    __shared__ float awl[200];
    int b = blockIdx.x, half = blockIdx.y, t = threadIdx.x;
    if (t < 200) awl[t] = aw[t * 64 + b];
    if (half == 0) {
        int wi = trg[b * TT + step];
        xcatB[b * 768 + t] = f2bf(emb[(size_t)wi * EE + t]);
    }
    __syncthreads();
    const float* base = s2 + (size_t)b * 512 + half * 256 + t;
    float a = 0;
#pragma unroll 8
    for (int s = 0; s < SS; ++s) a += awl[s] * base[(size_t)s * 64 * 512];
    xcatB[b * 768 + 256 + half * 256 + t] = f2bf(a);
}

// ---------------------------------------------------------------------------
// decoder GRU GEMMs via MFMA (bf16): 48 blocks x 4 waves = 192 wave-tiles.
// waves 0..95: gi = xcatB @ wihdB^T (K=768); 96..191: gh = hB @ whhdB^T (K=512)
// ---------------------------------------------------------------------------
__global__ __launch_bounds__(256) void k_grud_mfma(const u16* __restrict__ xcatB,
                                                   const u16* __restrict__ hB,
                                                   const u16* __restrict__ wihB,
                                                   const u16* __restrict__ whhB,
                                                   const float* __restrict__ bih,
                                                   const float* __restrict__ bhh,
                                                   float* __restrict__ gid_,
                                                   float* __restrict__ ghd) {
    int tid = threadIdx.x, w = tid >> 6, l = tid & 63;
    int g = blockIdx.x * 4 + w;
    bool second = g >= 96;
    int ntile = second ? g - 96 : g;
    const u16* A = second ? hB : xcatB;
    const u16* W = second ? whhB : wihB;
    const float* bias = second ? bhh : bih;
    float* out = second ? ghd : gid_;
    int K = second ? 512 : 768;
    int colsel = l & 15, kblk = l >> 4;
    const u16* bptr = W + (size_t)(ntile * 16 + colsel) * K + kblk * 8;
    const u16* aptr = A + (size_t)colsel * K + kblk * 8;
    float4v acc[4] = {};
    for (int k0 = 0; k0 < K; k0 += 32) {
        short8v bfrag = *(const short8v*)(bptr + k0);
#pragma unroll
        for (int mt = 0; mt < 4; ++mt) {
            short8v afrag = *(const short8v*)(aptr + (size_t)mt * 16 * K + k0);
            acc[mt] = __builtin_amdgcn_mfma_f32_16x16x32_bf16(afrag, bfrag, acc[mt], 0, 0, 0);
        }
    }
    int n = ntile * 16 + colsel;
    float bvv = bias[n];
#pragma unroll
    for (int mt = 0; mt < 4; ++mt)
#pragma unroll
        for (int q = 0; q < 4; ++q) {
            int row = mt * 16 + kblk * 4 + q;
            out[(size_t)row * 1536 + n] = acc[mt][q] + bvv;
        }
}

// ---------------------------------------------------------------------------
// decoder GRU elementwise update (h fp32 + bf16)
// ---------------------------------------------------------------------------
__global__ void k_hnew(const float* __restrict__ gi, const float* __restrict__ gh,
                       float* __restrict__ h, u16* __restrict__ hB) {
    int gid = blockIdx.x * 256 + threadIdx.x;  // 32768
    int b = gid >> 9, k = gid & 511;
    float gir = gi[b * 1536 + k], giz = gi[b * 1536 + 512 + k], gin = gi[b * 1536 + 1024 + k];
    float ghr = gh[b * 1536 + k], ghz = gh[b * 1536 + 512 + k], ghn = gh[b * 1536 + 1024 + k];
    float r = 1.f / (1.f + expf(-(gir + ghr)));
    float z = 1.f / (1.f + expf(-(giz + ghz)));
    float n = tanhf(gin + r * ghn);
    float hn = (1.f - z) * n + z * h[gid];
    h[gid] = hn;
    hB[gid] = f2bf(hn);
}

// ---------------------------------------------------------------------------
// vocab GEMM via MFMA + fused sum-exp / target capture.
// 500 blocks x 4 waves = 2000 n-tiles of 16. Per wave: 4 m-tiles over K=512.
// Logits are |.| <~ 2, so sum exp(logit) directly (no max subtraction).
// ---------------------------------------------------------------------------
__global__ __launch_bounds__(256) void k_vocab_mfma(const u16* __restrict__ hB,
                                                    const u16* __restrict__ WvB,
                                                    const float* __restrict__ bv,
                                                    const int* __restrict__ trg, int step,
                                                    float* __restrict__ psum,
                                                    float* __restrict__ tlog) {
    __shared__ int tgts[64];
    int tid = threadIdx.x;
    if (tid < 64) tgts[tid] = trg[tid * TT + step + 1];
    __syncthreads();
    int w = tid >> 6, l = tid & 63;
    int ntile = blockIdx.x * 4 + w;
    int colsel = l & 15, kblk = l >> 4;
    const u16* bptr = WvB + (size_t)(ntile * 16 + colsel) * 512 + kblk * 8;
    const u16* aptr = hB + (size_t)colsel * 512 + kblk * 8;
    float4v acc[4] = {};
    for (int k0 = 0; k0 < 512; k0 += 32) {
        short8v bfrag = *(const short8v*)(bptr + k0);
#pragma unroll
        for (int mt = 0; mt < 4; ++mt) {
            short8v afrag = *(const short8v*)(aptr + (size_t)mt * 16 * 512 + k0);
            acc[mt] = __builtin_amdgcn_mfma_f32_16x16x32_bf16(afrag, bfrag, acc[mt], 0, 0, 0);
        }
    }
    int col = ntile * 16 + colsel;
    float bvv = bv[col];
#pragma unroll
    for (int mt = 0; mt < 4; ++mt)
#pragma unroll
        for (int q = 0; q < 4; ++q) {
            int row = mt * 16 + kblk * 4 + q;
            float val = acc[mt][q] + bvv;
            if (tgts[row] == col) tlog[row] = val;
            float s = expf(val);
            s += __shfl_xor(s, 1, 64);
            s += __shfl_xor(s, 2, 64);
            s += __shfl_xor(s, 4, 64);
            s += __shfl_xor(s, 8, 64);
            if (colsel == 0) psum[(size_t)ntile * 64 + row] = s;
        }
}

// ---------------------------------------------------------------------------
// loss reduce: sum 2000 exp-sums per row -> log(S) - tlog
// ---------------------------------------------------------------------------
__global__ __launch_bounds__(256) void k_loss(const float* __restrict__ psum,
                                              const float* __restrict__ tlog,
                                              float* __restrict__ lossp) {
    __shared__ float red[64];
    int t = threadIdx.x;
    int b = t >> 2, q = t & 3;
    float s = 0.f;
    for (int nt = q; nt < 2000; nt += 4) s += psum[(size_t)nt * 64 + b];
    s += __shfl_xor(s, 1, 64);
    s += __shfl_xor(s, 2, 64);
    if (q == 0) red[b] = logf(s) - tlog[b];
    __syncthreads();
    if (t == 0) {
        float acc = 0;
        for (int i = 0; i < 64; ++i) acc += red[i];
        lossp[0] += acc;
    }
}

__global__ void k_final(const float* __restrict__ loss, float* __restrict__ out) {
    out[0] = loss[0] * (1.f / (64.f * 25.f));
}

// ---------------------------------------------------------------------------
extern "C" void kernel_launch(void* const* d_in, const int* in_sizes, int n_in,
                              void* d_out, int out_size, void* d_ws, size_t ws_size,
                              hipStream_t stream) {
    const int* src = (const int*)d_in[0];
    const int* trg = (const int*)d_in[1];
    const float* emb = (const float*)d_in[2];
    const float* w_ih_f = (const float*)d_in[3];
    const float* w_hh_f = (const float*)d_in[4];
    const float* b_ih_f = (const float*)d_in[5];
    const float* b_hh_f = (const float*)d_in[6];
    const float* w_ih_b = (const float*)d_in[7];
    const float* w_hh_b = (const float*)d_in[8];
    const float* b_ih_b = (const float*)d_in[9];
    const float* b_hh_b = (const float*)d_in[10];
    const float* W1 = (const float*)d_in[11];
    const float* b1 = (const float*)d_in[12];
    const float* W2 = (const float*)d_in[13];
    const float* b2 = (const float*)d_in[14];
    const float* w_ih_d = (const float*)d_in[15];
    const float* w_hh_d = (const float*)d_in[16];
    const float* b_ih_d = (const float*)d_in[17];
    const float* b_hh_d = (const float*)d_in[18];
    const float* Wv = (const float*)d_in[19];
    const float* bv = (const float*)d_in[20];
    const float* Wa1 = (const float*)d_in[21];
    const float* ba1 = (const float*)d_in[22];
    const float* Wa2 = (const float*)d_in[23];
    const float* ba2 = (const float*)d_in[24];

    float* ws = (float*)d_ws;
    float* giF = ws;                            // 9,830,400
    float* giB = giF + 9830400;                 // 9,830,400
    float* states = giB + 9830400;              // 6,553,600
    float* states2 = states + 6553600;          // 6,553,600
    float* wT16f_f = states2 + 6553600;         // 98,304 (uint)
    float* wT16b_f = wT16f_f + 98304;           // 98,304 (uint)
    float* ench = wT16b_f + 98304;              // 32,768
    float* G = ench + 32768;                    // 32,768
    float* attn1 = G + 32768;                   // 12,800
    float* aw = attn1 + 12800;                  // 12,800
    float* xcatB_f = aw + 12800;                // 24,576 slots (49,152 u16)
    float* hdec = xcatB_f + 24576;              // 32,768
    float* hB_f = hdec + 32768;                 // 16,384 slots (32,768 u16)
    float* gid_ = hB_f + 16384;                 // 98,304
    float* ghd = gid_ + 98304;                  // 98,304
    float* psum = ghd + 98304;                  // 128,000
    float* tlog = psum + 128000;                // 64
    float* lossp = tlog + 64;                   // 1
    u32* wT16f = (u32*)wT16f_f;
    u32* wT16b = (u32*)wT16b_f;
    u16* xcatB = (u16*)xcatB_f;
    u16* hB = (u16*)hB_f;
    // aliases, valid only after k_scan16 (gi dead):
    u16* WvB = (u16*)giF;                       // 16,384,000 u16 (< giF span)
    u16* wihdB = (u16*)giB;                     // 1,179,648 u16
    u16* whhdB = (u16*)(giB + 1000000);         // 786,432 u16

    k_whh_pack16<<<768, 256, 0, stream>>>(w_hh_f, w_hh_b, wT16f, wT16b);
    k_gemm_gi<<<dim3(12, 200), 256, 0, stream>>>(src, emb, w_ih_f, b_ih_f, giF);
    k_gemm_gi<<<dim3(12, 200), 256, 0, stream>>>(src, emb, w_ih_b, b_ih_b, giB);
    k_scan16<<<64, 512, 0, stream>>>(giF, giB, wT16f, wT16b, b_hh_f, b_hh_b, states);
    // weight conversions (overwrite gi regions, now dead)
    k_tobf<<<64000, 256, 0, stream>>>(Wv, WvB, VV * HID);
    k_tobf<<<4608, 256, 0, stream>>>(w_ih_d, wihdB, 1536 * 768);
    k_tobf<<<3072, 256, 0, stream>>>(w_hh_d, whhdB, 1536 * 512);
    k_ench<<<64, 256, 0, stream>>>(states, W2, b2, ench, G);
    k_gate<<<dim3(8, 200), 256, 0, stream>>>(states, W1, b1, G, states2);
    k_attn1<<<3200, 256, 0, stream>>>(states2, Wa1, ba1, attn1);
    k_dec_init<<<128, 256, 0, stream>>>(ench, hdec, hB, lossp);

    for (int t = 0; t < TT - 1; ++t) {
        k_attn_soft<<<64, 256, 0, stream>>>(hdec, Wa2, ba2, attn1, aw);
        k_ctx<<<dim3(64, 2), 256, 0, stream>>>(aw, states2, emb, trg, t, xcatB);
        k_grud_mfma<<<48, 256, 0, stream>>>(xcatB, hB, wihdB, whhdB, b_ih_d, b_hh_d, gid_, ghd);
        k_hnew<<<128, 256, 0, stream>>>(gid_, ghd, hdec, hB);
        k_vocab_mfma<<<500, 256, 0, stream>>>(hB, WvB, bv, trg, t, psum, tlog);
        k_loss<<<1, 256, 0, stream>>>(psum, tlog, lossp);
    }
    k_final<<<1, 1, 0, stream>>>(lossp, (float*)d_out);
}

// Round 6
// 2281.666 us; speedup vs baseline: 3.1172x; 2.4899x over previous
//
#include <hip/hip_runtime.h>
#include <math.h>

#define BB 64
#define SS 200
#define TT 25
#define VV 32000
#define EE 256
#define HH 256
#define HID 512

typedef unsigned int u32;
typedef unsigned short u16;
typedef _Float16 half2v __attribute__((ext_vector_type(2)));
typedef short short8v __attribute__((ext_vector_type(8)));
typedef float float4v __attribute__((ext_vector_type(4)));

__device__ inline half2v u2h2(u32 u) { half2v h; __builtin_memcpy(&h, &u, 4); return h; }
__device__ inline u32 packh2(float a, float b) {
    _Float16 ha = (_Float16)a, hb = (_Float16)b;
    u16 ua, ub;
    __builtin_memcpy(&ua, &ha, 2);
    __builtin_memcpy(&ub, &hb, 2);
    return (u32)ua | ((u32)ub << 16);
}
__device__ inline u16 f2bf(float x) {
    u32 u = __float_as_uint(x);
    return (u16)((u + 0x7fff + ((u >> 16) & 1)) >> 16);
}

#if defined(__has_builtin)
#if __has_builtin(__builtin_amdgcn_fdot2)
#define HAS_FDOT2 1
#endif
#endif
#ifdef HAS_FDOT2
#define DOT2(acc, wu, hu) acc = __builtin_amdgcn_fdot2(u2h2(wu), u2h2(hu), acc, false)
#else
#define DOT2(acc, wu, hu)                                             \
    {                                                                 \
        half2v _w = u2h2(wu), _h = u2h2(hu);                          \
        acc += (float)_w.x * (float)_h.x + (float)_w.y * (float)_h.y; \
    }
#endif

// ---------------------------------------------------------------------------
// generic f32 -> bf16 convert
// ---------------------------------------------------------------------------
__global__ void k_tobf(const float* __restrict__ src, u16* __restrict__ dst, int n) {
    int i = blockIdx.x * 256 + threadIdx.x;
    if (i < n) dst[i] = f2bf(src[i]);
}

// ---------------------------------------------------------------------------
// pack w_hh (768x256 f32) -> f16 pairs, layout wPK[kp][j] (kp = K-pair 0..127)
// ---------------------------------------------------------------------------
__global__ void k_whh_pack16(const float* __restrict__ wf, const float* __restrict__ wb,
                             u32* __restrict__ oF, u32* __restrict__ oB) {
    int gid = blockIdx.x * 256 + threadIdx.x;
    if (gid >= 2 * 768 * 128) return;
    const float* w = (gid < 768 * 128) ? wf : wb;
    u32* o = (gid < 768 * 128) ? oF : oB;
    int g = gid % (768 * 128);
    int kp = g / 768;
    int j = g % 768;
    o[g] = packh2(w[j * 256 + 2 * kp], w[j * 256 + 2 * kp + 1]);
}

// ---------------------------------------------------------------------------
// gi GEMM via MFMA (bf16): C[12800][768] = gather(embB by src) @ WB^T + bias
// ---------------------------------------------------------------------------
__global__ __launch_bounds__(256) void k_gi_mfma(const int* __restrict__ src,
                                                 const u16* __restrict__ embB,
                                                 const u16* __restrict__ WB,
                                                 const float* __restrict__ bias,
                                                 float* __restrict__ C) {
    __shared__ int toks[64];
    int tid = threadIdx.x, bx = blockIdx.x, by = blockIdx.y;
    if (tid < 64) toks[tid] = src[by * 64 + tid];
    __syncthreads();
    int w = tid >> 6, l = tid & 63, colsel = l & 15, kblk = l >> 4;
    int n = bx * 64 + w * 16 + colsel;
    const u16* bptr = WB + (size_t)n * 256 + kblk * 8;
    int tk[4];
#pragma unroll
    for (int mt = 0; mt < 4; ++mt) tk[mt] = toks[mt * 16 + colsel];
    float4v acc[4] = {};
    for (int k0 = 0; k0 < 256; k0 += 32) {
        short8v bfrag = *(const short8v*)(bptr + k0);
#pragma unroll
        for (int mt = 0; mt < 4; ++mt) {
            short8v afrag = *(const short8v*)(embB + (size_t)tk[mt] * 256 + kblk * 8 + k0);
            acc[mt] = __builtin_amdgcn_mfma_f32_16x16x32_bf16(afrag, bfrag, acc[mt], 0, 0, 0);
        }
    }
    float bvv = bias[n];
#pragma unroll
    for (int mt = 0; mt < 4; ++mt)
#pragma unroll
        for (int q = 0; q < 4; ++q) {
            int m = by * 64 + mt * 16 + kblk * 4 + q;
            C[(size_t)m * 768 + n] = acc[mt][q] + bvv;
        }
}

// ---------------------------------------------------------------------------
// recurrent scan, register-resident W: 128 blocks x 1024 thr, 1 chain/block.
// thread (e = tid&255, kq = tid>>8) holds W rows {e,256+e,512+e} over
// K-quarter kq as 96 packed f16-pair u32s in VGPRs.  h in LDS (packed half2).
// ---------------------------------------------------------------------------
__global__ __launch_bounds__(1024, 4) void k_scan_reg(const float* __restrict__ giF,
                                                      const float* __restrict__ giB,
                                                      const u32* __restrict__ wPKf,
                                                      const u32* __restrict__ wPKb,
                                                      const float* __restrict__ bhhf,
                                                      const float* __restrict__ bhhb,
                                                      float* __restrict__ states) {
    __shared__ u32 hs2[128];
    __shared__ float pacc[3][3][256];
    int tid = threadIdx.x, bid = blockIdx.x;
    int e = tid & 255, kq = tid >> 8;
    int dir = bid >> 6, j = bid & 63;
    const float* gi = dir ? giB : giF;
    const u32* wPK = dir ? wPKb : wPKf;
    const float* bhh = dir ? bhhb : bhhf;
    u32 wr[32], wz[32], wn[32];
#pragma unroll
    for (int i = 0; i < 32; ++i) {
        int kp = kq * 32 + i;
        wr[i] = wPK[kp * 768 + e];
        wz[i] = wPK[kp * 768 + 256 + e];
        wn[i] = wPK[kp * 768 + 512 + e];
    }
    float br = 0.f, bz = 0.f, bn = 0.f, hprev = 0.f;
    if (kq == 0) {
        br = bhh[e]; bz = bhh[256 + e]; bn = bhh[512 + e];
        if (e < 128) hs2[e] = 0u;
    }
    __syncthreads();
    for (int s = 0; s < SS; ++s) {
        int srow = dir ? (SS - 1 - s) : s;
        float gir = 0, giz = 0, gin = 0;
        if (kq == 0) {
            const float* g0 = gi + ((size_t)srow * 64 + j) * 768;
            gir = g0[e]; giz = g0[256 + e]; gin = g0[512 + e];
        }
        float ar = 0, az = 0, an = 0;
#pragma unroll
        for (int i4 = 0; i4 < 8; ++i4) {
            uint4 hv = *(const uint4*)&hs2[kq * 32 + i4 * 4];
            DOT2(ar, wr[i4 * 4 + 0], hv.x); DOT2(az, wz[i4 * 4 + 0], hv.x); DOT2(an, wn[i4 * 4 + 0], hv.x);
            DOT2(ar, wr[i4 * 4 + 1], hv.y); DOT2(az, wz[i4 * 4 + 1], hv.y); DOT2(an, wn[i4 * 4 + 1], hv.y);
            DOT2(ar, wr[i4 * 4 + 2], hv.z); DOT2(az, wz[i4 * 4 + 2], hv.z); DOT2(an, wn[i4 * 4 + 2], hv.z);
            DOT2(ar, wr[i4 * 4 + 3], hv.w); DOT2(az, wz[i4 * 4 + 3], hv.w); DOT2(an, wn[i4 * 4 + 3], hv.w);
        }
        if (kq > 0) {
            pacc[kq - 1][0][e] = ar; pacc[kq - 1][1][e] = az; pacc[kq - 1][2][e] = an;
        }
        __syncthreads();
        if (kq == 0) {
            float sr = ar + pacc[0][0][e] + pacc[1][0][e] + pacc[2][0][e];
            float sz = az + pacc[0][1][e] + pacc[1][1][e] + pacc[2][1][e];
            float sn = an + pacc[0][2][e] + pacc[1][2][e] + pacc[2][2][e];
            float r = 1.f / (1.f + expf(-(gir + sr + br)));
            float z = 1.f / (1.f + expf(-(giz + sz + bz)));
            float n = tanhf(gin + r * (sn + bn));
            float hn = (1.f - z) * n + z * hprev;
            hprev = hn;
            states[((size_t)srow * 64 + j) * HID + dir * 256 + e] = hn;
            float hnb = __shfl_down(hn, 1, 64);
            if ((e & 1) == 0) hs2[e >> 1] = packh2(hn, hnb);
        }
        __syncthreads();
    }
}

// ---------------------------------------------------------------------------
// ench (scrambled enc_hidden reshape) + G = ench @ W2^T + b2
// ---------------------------------------------------------------------------
__global__ __launch_bounds__(256) void k_ench(const float* __restrict__ states,
                                              const float* __restrict__ W2,
                                              const float* __restrict__ b2,
                                              float* __restrict__ ench,
                                              float* __restrict__ G) {
    __shared__ float es[512];
    int b = blockIdx.x, t = threadIdx.x;
    int p0 = 2 * b, p1 = 2 * b + 1;
    float v0 = (p0 < 64) ? states[((size_t)(SS - 1) * 64 + p0) * HID + t]
                         : states[((size_t)(p0 - 64)) * HID + 256 + t];
    float v1 = (p1 < 64) ? states[((size_t)(SS - 1) * 64 + p1) * HID + t]
                         : states[((size_t)(p1 - 64)) * HID + 256 + t];
    es[t] = v0; es[256 + t] = v1;
    ench[b * 512 + t] = v0; ench[b * 512 + 256 + t] = v1;
    __syncthreads();
    float a0 = 0, a1 = 0;
    for (int k = 0; k < 512; k += 4) {
        float4 e = *(const float4*)&es[k];
        float4 w0 = *(const float4*)(W2 + (size_t)t * 512 + k);
        float4 w1 = *(const float4*)(W2 + (size_t)(256 + t) * 512 + k);
        a0 += e.x * w0.x + e.y * w0.y + e.z * w0.z + e.w * w0.w;
        a1 += e.x * w1.x + e.y * w1.y + e.z * w1.z + e.w * w1.w;
    }
    G[b * 512 + t] = a0 + b2[t];
    G[b * 512 + 256 + t] = a1 + b2[256 + t];
}

// ---------------------------------------------------------------------------
// gate GEMM via MFMA: states2 = states * sigmoid(statesB @ W1B^T + b1 + G[b])
// ---------------------------------------------------------------------------
__global__ __launch_bounds__(256) void k_gate_mfma(const u16* __restrict__ statesB,
                                                   const float* __restrict__ states,
                                                   const u16* __restrict__ W1B,
                                                   const float* __restrict__ b1,
                                                   const float* __restrict__ G,
                                                   float* __restrict__ out) {
    int tid = threadIdx.x, bx = blockIdx.x, by = blockIdx.y;
    int w = tid >> 6, l = tid & 63, colsel = l & 15, kblk = l >> 4;
    int n = bx * 64 + w * 16 + colsel;
    const u16* bptr = W1B + (size_t)n * 512 + kblk * 8;
    const u16* aptr = statesB + ((size_t)by * 64 + colsel) * 512 + kblk * 8;
    float4v acc[4] = {};
    for (int k0 = 0; k0 < 512; k0 += 32) {
        short8v bfrag = *(const short8v*)(bptr + k0);
#pragma unroll
        for (int mt = 0; mt < 4; ++mt) {
            short8v afrag = *(const short8v*)(aptr + (size_t)mt * 16 * 512 + k0);
            acc[mt] = __builtin_amdgcn_mfma_f32_16x16x32_bf16(afrag, bfrag, acc[mt], 0, 0, 0);
        }
    }
    float b1v = b1[n];
#pragma unroll
    for (int mt = 0; mt < 4; ++mt)
#pragma unroll
        for (int q = 0; q < 4; ++q) {
            int bloc = mt * 16 + kblk * 4 + q;       // m % 64
            int m = by * 64 + bloc;
            float x = acc[mt][q] + b1v + G[(size_t)bloc * 512 + n];
            float g = 1.f / (1.f + expf(-x));
            out[(size_t)m * 512 + n] = states[(size_t)m * 512 + n] * g;
        }
}

// ---------------------------------------------------------------------------
// attn1[m] = dot(states2[m], Wa1) + ba1
// ---------------------------------------------------------------------------
__global__ __launch_bounds__(256) void k_attn1(const float* __restrict__ s2,
                                               const float* __restrict__ Wa1,
                                               const float* __restrict__ ba1,
                                               float* __restrict__ attn1) {
    int wid = threadIdx.x >> 6, lane = threadIdx.x & 63;
    int m = blockIdx.x * 4 + wid;
    const float* row = s2 + (size_t)m * 512;
    float acc = 0;
    for (int i = lane; i < 512; i += 64) acc += row[i] * Wa1[i];
    for (int off = 32; off > 0; off >>= 1) acc += __shfl_down(acc, off, 64);
    if (lane == 0) attn1[m] = acc + ba1[0];
}

// ---------------------------------------------------------------------------
// decoder init: h = ench (fp32 + bf16), loss = 0
// ---------------------------------------------------------------------------
__global__ void k_dec_init(const float* __restrict__ ench, float* __restrict__ h,
                           u16* __restrict__ hB, float* __restrict__ loss) {
    int gid = blockIdx.x * 256 + threadIdx.x;
    if (gid < 64 * 512) {
        float v = ench[gid];
        h[gid] = v;
        hB[gid] = f2bf(v);
    }
    if (gid == 0) loss[0] = 0.f;
}

// ---------------------------------------------------------------------------
// attention scores + faithful scrambled softmax (block = softmax row r)
// ---------------------------------------------------------------------------
__global__ __launch_bounds__(256) void k_attn_soft(const float* __restrict__ h,
                                                   const float* __restrict__ Wa2,
                                                   const float* __restrict__ ba2,
                                                   const float* __restrict__ attn1,
                                                   float* __restrict__ aw) {
    __shared__ float a2s[64];
    __shared__ float red[256];
    int r = blockIdx.x, t = threadIdx.x;
    int b = t >> 2, q = t & 3;
    float part = 0;
    for (int i = 0; i < 128; ++i) {
        int k = q + 4 * i;
        part += h[(size_t)b * 512 + k] * Wa2[k];
    }
    red[t] = part;
    __syncthreads();
    if (t < 64) a2s[t] = red[t * 4] + red[t * 4 + 1] + red[t * 4 + 2] + red[t * 4 + 3] + ba2[0];
    __syncthreads();
    int iflat = r * 200 + t;
    float val = (t < 200) ? attn1[iflat] + a2s[iflat & 63] : -3.4e38f;
    red[t] = val;
    __syncthreads();
    for (int s = 128; s > 0; s >>= 1) {
        if (t < s) red[t] = fmaxf(red[t], red[t + s]);
        __syncthreads();
    }
    float mx = red[0];
    __syncthreads();
    float e = (t < 200) ? expf(val - mx) : 0.f;
    red[t] = e;
    __syncthreads();
    for (int s = 128; s > 0; s >>= 1) {
        if (t < s) red[t] += red[t + s];
        __syncthreads();
    }
    float sum = red[0];
    if (t < 200) aw[iflat] = e / sum;
}

// ---------------------------------------------------------------------------
// context + xcat build: float4 coalesced, 2 s-streams per block. grid 64.
// ---------------------------------------------------------------------------
__global__ __launch_bounds__(256) void k_ctx(const float* __restrict__ aw,
                                             const float* __restrict__ s2,
                                             const float* __restrict__ emb,
                                             const int* __restrict__ trg,
                                             int step, u16* __restrict__ xcatB) {
    __shared__ float awl[200];
    __shared__ float4 ctx4[128];
    int b = blockIdx.x, t = threadIdx.x;
    if (t < 200) awl[t] = aw[t * 64 + b];
    {
        int wi = trg[b * TT + step];
        xcatB[b * 768 + t] = f2bf(emb[(size_t)wi * EE + t]);
    }
    __syncthreads();
    int half = t >> 7, d4 = t & 127;
    float ax = 0, ay = 0, az = 0, aww = 0;
#pragma unroll 4
    for (int s = half; s < SS; s += 2) {
        float wgt = awl[s];
        float4 v = *(const float4*)(s2 + ((size_t)s * 64 + b) * 512 + d4 * 4);
        ax += wgt * v.x; ay += wgt * v.y; az += wgt * v.z; aww += wgt * v.w;
    }
    if (half == 0) { float4 f; f.x = ax; f.y = ay; f.z = az; f.w = aww; ctx4[d4] = f; }
    __syncthreads();
    if (half == 1) {
        float4 o = ctx4[d4];
        o.x += ax; o.y += ay; o.z += az; o.w += aww;
        u16* dst = xcatB + b * 768 + 256 + d4 * 4;
        dst[0] = f2bf(o.x); dst[1] = f2bf(o.y); dst[2] = f2bf(o.z); dst[3] = f2bf(o.w);
    }
}

// ---------------------------------------------------------------------------
// decoder GRU GEMMs via MFMA (bf16)
// ---------------------------------------------------------------------------
__global__ __launch_bounds__(256) void k_grud_mfma(const u16* __restrict__ xcatB,
                                                   const u16* __restrict__ hB,
                                                   const u16* __restrict__ wihB,
                                                   const u16* __restrict__ whhB,
                                                   const float* __restrict__ bih,
                                                   const float* __restrict__ bhh,
                                                   float* __restrict__ gid_,
                                                   float* __restrict__ ghd) {
    int tid = threadIdx.x, w = tid >> 6, l = tid & 63;
    int g = blockIdx.x * 4 + w;
    bool second = g >= 96;
    int ntile = second ? g - 96 : g;
    const u16* A = second ? hB : xcatB;
    const u16* W = second ? whhB : wihB;
    const float* bias = second ? bhh : bih;
    float* out = second ? ghd : gid_;
    int K = second ? 512 : 768;
    int colsel = l & 15, kblk = l >> 4;
    const u16* bptr = W + (size_t)(ntile * 16 + colsel) * K + kblk * 8;
    const u16* aptr = A + (size_t)colsel * K + kblk * 8;
    float4v acc[4] = {};
    for (int k0 = 0; k0 < K; k0 += 32) {
        short8v bfrag = *(const short8v*)(bptr + k0);
#pragma unroll
        for (int mt = 0; mt < 4; ++mt) {
            short8v afrag = *(const short8v*)(aptr + (size_t)mt * 16 * K + k0);
            acc[mt] = __builtin_amdgcn_mfma_f32_16x16x32_bf16(afrag, bfrag, acc[mt], 0, 0, 0);
        }
    }
    int n = ntile * 16 + colsel;
    float bvv = bias[n];
#pragma unroll
    for (int mt = 0; mt < 4; ++mt)
#pragma unroll
        for (int q = 0; q < 4; ++q) {
            int row = mt * 16 + kblk * 4 + q;
            out[(size_t)row * 1536 + n] = acc[mt][q] + bvv;
        }
}

// ---------------------------------------------------------------------------
// decoder GRU elementwise update (h fp32 + bf16)
// ---------------------------------------------------------------------------
__global__ void k_hnew(const float* __restrict__ gi, const float* __restrict__ gh,
                       float* __restrict__ h, u16* __restrict__ hB) {
    int gid = blockIdx.x * 256 + threadIdx.x;  // 32768
    int b = gid >> 9, k = gid & 511;
    float gir = gi[b * 1536 + k], giz = gi[b * 1536 + 512 + k], gin = gi[b * 1536 + 1024 + k];
    float ghr = gh[b * 1536 + k], ghz = gh[b * 1536 + 512 + k], ghn = gh[b * 1536 + 1024 + k];
    float r = 1.f / (1.f + expf(-(gir + ghr)));
    float z = 1.f / (1.f + expf(-(giz + ghz)));
    float n = tanhf(gin + r * ghn);
    float hn = (1.f - z) * n + z * h[gid];
    h[gid] = hn;
    hB[gid] = f2bf(hn);
}

// ---------------------------------------------------------------------------
// vocab GEMM via MFMA + fused exp-sum partials (per-block, transposed layout)
// psumA[step][row][500]; tlogA[step][row]
// ---------------------------------------------------------------------------
__global__ __launch_bounds__(256) void k_vocab_mfma(const u16* __restrict__ hB,
                                                    const u16* __restrict__ WvB,
                                                    const float* __restrict__ bv,
                                                    const int* __restrict__ trg, int step,
                                                    float* __restrict__ psumA,
                                                    float* __restrict__ tlogA) {
    __shared__ int tgts[64];
    __shared__ float sred[4][64];
    int tid = threadIdx.x;
    if (tid < 64) tgts[tid] = trg[tid * TT + step + 1];
    __syncthreads();
    int w = tid >> 6, l = tid & 63;
    int ntile = blockIdx.x * 4 + w;
    int colsel = l & 15, kblk = l >> 4;
    const u16* bptr = WvB + (size_t)(ntile * 16 + colsel) * 512 + kblk * 8;
    const u16* aptr = hB + (size_t)colsel * 512 + kblk * 8;
    float4v acc[4] = {};
    for (int k0 = 0; k0 < 512; k0 += 32) {
        short8v bfrag = *(const short8v*)(bptr + k0);
#pragma unroll
        for (int mt = 0; mt < 4; ++mt) {
            short8v afrag = *(const short8v*)(aptr + (size_t)mt * 16 * 512 + k0);
            acc[mt] = __builtin_amdgcn_mfma_f32_16x16x32_bf16(afrag, bfrag, acc[mt], 0, 0, 0);
        }
    }
    int col = ntile * 16 + colsel;
    float bvv = bv[col];
#pragma unroll
    for (int mt = 0; mt < 4; ++mt)
#pragma unroll
        for (int q = 0; q < 4; ++q) {
            int row = mt * 16 + kblk * 4 + q;
            float val = acc[mt][q] + bvv;
            if (tgts[row] == col) tlogA[step * 64 + row] = val;
            float s = expf(val);
            s += __shfl_xor(s, 1, 64);
            s += __shfl_xor(s, 2, 64);
            s += __shfl_xor(s, 4, 64);
            s += __shfl_xor(s, 8, 64);
            if (colsel == 0) sred[w][row] = s;
        }
    __syncthreads();
    if (tid < 64)
        psumA[(size_t)step * 32000 + tid * 500 + blockIdx.x] =
            sred[0][tid] + sred[1][tid] + sred[2][tid] + sred[3][tid];
}

// ---------------------------------------------------------------------------
// loss reduce over all steps at once: grid (24, 64)
// ---------------------------------------------------------------------------
__global__ __launch_bounds__(256) void k_loss_all(const float* __restrict__ psumA,
                                                  const float* __restrict__ tlogA,
                                                  float* __restrict__ lossp) {
    __shared__ float red[4];
    int tt = blockIdx.x, b = blockIdx.y, t = threadIdx.x;
    float v = 0;
    for (int i = t; i < 500; i += 256) v += psumA[(size_t)tt * 32000 + b * 500 + i];
    for (int off = 32; off > 0; off >>= 1) v += __shfl_down(v, off, 64);
    if ((t & 63) == 0) red[t >> 6] = v;
    __syncthreads();
    if (t == 0) {
        float S = red[0] + red[1] + red[2] + red[3];
        atomicAdd(lossp, logf(S) - tlogA[tt * 64 + b]);
    }
}

__global__ void k_final(const float* __restrict__ loss, float* __restrict__ out) {
    out[0] = loss[0] * (1.f / (64.f * 25.f));
}

// ---------------------------------------------------------------------------
extern "C" void kernel_launch(void* const* d_in, const int* in_sizes, int n_in,
                              void* d_out, int out_size, void* d_ws, size_t ws_size,
                              hipStream_t stream) {
    const int* src = (const int*)d_in[0];
    const int* trg = (const int*)d_in[1];
    const float* emb = (const float*)d_in[2];
    const float* w_ih_f = (const float*)d_in[3];
    const float* w_hh_f = (const float*)d_in[4];
    const float* b_ih_f = (const float*)d_in[5];
    const float* b_hh_f = (const float*)d_in[6];
    const float* w_ih_b = (const float*)d_in[7];
    const float* w_hh_b = (const float*)d_in[8];
    const float* b_ih_b = (const float*)d_in[9];
    const float* b_hh_b = (const float*)d_in[10];
    const float* W1 = (const float*)d_in[11];
    const float* b1 = (const float*)d_in[12];
    const float* W2 = (const float*)d_in[13];
    const float* b2 = (const float*)d_in[14];
    const float* w_ih_d = (const float*)d_in[15];
    const float* w_hh_d = (const float*)d_in[16];
    const float* b_ih_d = (const float*)d_in[17];
    const float* b_hh_d = (const float*)d_in[18];
    const float* Wv = (const float*)d_in[19];
    const float* bv = (const float*)d_in[20];
    const float* Wa1 = (const float*)d_in[21];
    const float* ba1 = (const float*)d_in[22];
    const float* Wa2 = (const float*)d_in[23];
    const float* ba2 = (const float*)d_in[24];

    float* ws = (float*)d_ws;
    float* giF = ws;                           // 9,830,400
    float* giB = giF + 9830400;                // 9,830,400
    float* states = giB + 9830400;             // 6,553,600
    float* states2 = states + 6553600;         // 6,553,600 (embB aliases head)
    float* wPKf_f = states2 + 6553600;         // 98,304 (u32)
    float* wPKb_f = wPKf_f + 98304;            // 98,304 (u32)
    float* ench = wPKb_f + 98304;              // 32,768
    float* G = ench + 32768;                   // 32,768
    float* attn1 = G + 32768;                  // 12,800
    float* aw = attn1 + 12800;                 // 12,800
    float* xcatB_f = aw + 12800;               // 24,576 slots (49,152 u16)
    float* hdec = xcatB_f + 24576;             // 32,768
    float* hB_f = hdec + 32768;                // 16,384 slots
    float* gid_ = hB_f + 16384;                // 98,304
    float* ghd = gid_ + 98304;                 // 98,304
    float* psumA = ghd + 98304;                // 768,000 (24*64*500)
    float* tlogA = psumA + 768000;             // 1,536
    float* lossp = tlogA + 1536;               // 1
    float* wihfB_f = lossp + 1;                // 98,304 slots
    float* wihbB_f = wihfB_f + 98304;          // 98,304 slots
    float* W1B_f = wihbB_f + 98304;            // 131,072 slots

    u32* wPKf = (u32*)wPKf_f;
    u32* wPKb = (u32*)wPKb_f;
    u16* xcatB = (u16*)xcatB_f;
    u16* hB = (u16*)hB_f;
    u16* wihfB = (u16*)wihfB_f;
    u16* wihbB = (u16*)wihbB_f;
    u16* W1B = (u16*)W1B_f;
    u16* embB = (u16*)states2;                 // 8,192,000 u16 = 4,096,000 fslots <= 6,553,600 OK; dead before gate
    // aliases valid only after k_scan_reg (gi regions dead):
    u16* WvB = (u16*)giF;                      // 16,384,000 u16 = 8,192,000 fslots <= 9,830,400 OK
    u16* wihdB = (u16*)giB;                    // 1,179,648 u16 = 589,824 fslots
    u16* whhdB = (u16*)(giB + 589824);         // 786,432 u16 = 393,216 fslots, ends 983,040
    u16* statesB = (u16*)(giB + 1000000);      // 6,553,600 u16 = 3,276,800 fslots, ends 4,276,800 <= 9,830,400 OK

    // prep + conversions needed before the encoder
    k_whh_pack16<<<768, 256, 0, stream>>>(w_hh_f, w_hh_b, wPKf, wPKb);
    k_tobf<<<32000, 256, 0, stream>>>(emb, embB, VV * EE);
    k_tobf<<<768, 256, 0, stream>>>(w_ih_f, wihfB, 768 * 256);
    k_tobf<<<768, 256, 0, stream>>>(w_ih_b, wihbB, 768 * 256);
    k_tobf<<<1024, 256, 0, stream>>>(W1, W1B, 512 * 512);

    k_gi_mfma<<<dim3(12, 200), 256, 0, stream>>>(src, embB, wihfB, b_ih_f, giF);
    k_gi_mfma<<<dim3(12, 200), 256, 0, stream>>>(src, embB, wihbB, b_ih_b, giB);
    k_scan_reg<<<128, 1024, 0, stream>>>(giF, giB, wPKf, wPKb, b_hh_f, b_hh_b, states);

    // conversions that overwrite gi regions (dead after scan)
    k_tobf<<<64000, 256, 0, stream>>>(Wv, WvB, VV * HID);
    k_tobf<<<4608, 256, 0, stream>>>(w_ih_d, wihdB, 1536 * 768);
    k_tobf<<<3072, 256, 0, stream>>>(w_hh_d, whhdB, 1536 * 512);
    k_tobf<<<25600, 256, 0, stream>>>(states, statesB, 12800 * 512);

    k_ench<<<64, 256, 0, stream>>>(states, W2, b2, ench, G);
    k_gate_mfma<<<dim3(8, 200), 256, 0, stream>>>(statesB, states, W1B, b1, G, states2);
    k_attn1<<<3200, 256, 0, stream>>>(states2, Wa1, ba1, attn1);
    k_dec_init<<<128, 256, 0, stream>>>(ench, hdec, hB, lossp);

    for (int t = 0; t < TT - 1; ++t) {
        k_attn_soft<<<64, 256, 0, stream>>>(hdec, Wa2, ba2, attn1, aw);
        k_ctx<<<64, 256, 0, stream>>>(aw, states2, emb, trg, t, xcatB);
        k_grud_mfma<<<48, 256, 0, stream>>>(xcatB, hB, wihdB, whhdB, b_ih_d, b_hh_d, gid_, ghd);
        k_hnew<<<128, 256, 0, stream>>>(gid_, ghd, hdec, hB);
        k_vocab_mfma<<<500, 256, 0, stream>>>(hB, WvB, bv, trg, t, psumA, tlogA);
    }
    k_loss_all<<<dim3(24, 64), 256, 0, stream>>>(psumA, tlogA, lossp);
    k_final<<<1, 1, 0, stream>>>(lossp, (float*)d_out);
}